// Round 10
// baseline (292.565 us; speedup 1.0000x reference)
//
#include <hip/hip_runtime.h>
#include <hip/hip_bf16.h>

#define N_NODES 8192
#define E_EDGES 262144
#define HID 128
#define FIN 256
#define CAP 128     // fixed CSR bin capacity; deg ~ Binom(262144,1/8192), max ~60
#define GRID_P 1024 // prep grid: 4 blocks/CU x 256 CUs -> co-resident by construction

typedef __attribute__((ext_vector_type(8))) short bf16x8;
typedef __attribute__((ext_vector_type(4))) float f32x4;

// device-scope grid barrier; requires all GRID_P blocks co-resident.
__device__ inline void gridbar(unsigned* bar, unsigned target) {
    __syncthreads();
    if (threadIdx.x == 0) {
        __threadfence();  // release: make this block's writes visible
        atomicAdd(bar, 1u);  // device-scope by default (m20)
        while (__hip_atomic_load(bar, __ATOMIC_RELAXED, __HIP_MEMORY_SCOPE_AGENT) < target)
            __builtin_amdgcn_s_sleep(8);
        __threadfence();  // acquire: see other blocks' writes
    }
    __syncthreads();
}

// ---- fused prep: [scatter(all) + xw(bid<512)] -> gridbar -> agg(8 rows/block) ----
__global__ __launch_bounds__(256, 4) void prep_fused(
    const float* __restrict__ x, const float* __restrict__ W,
    const int* __restrict__ src, const int* __restrict__ dst,
    unsigned* __restrict__ cursor, int* __restrict__ csr_src,
    const float* __restrict__ b, float* __restrict__ z_out,
    __hip_bfloat16* __restrict__ zb, float* __restrict__ h,
    unsigned* __restrict__ bar) {
    int bid = blockIdx.x;
    int tid = threadIdx.x;

    // ---- phase 1a: scatter 256 edges per block (E_EDGES == GRID_P*256) ----
    {
        int e = bid * 256 + tid;
        int d = dst[e];
        unsigned pos = atomicAdd(&cursor[d], 1u);
        csr_src[(size_t)d * CAP + pos] = src[e];
    }

    // ---- phase 1b: xw for blocks 0..511 (16 rows each) ----
    if (bid < 512) {
        int col = tid & 127;
        int row0 = bid * 16 + (tid >> 7) * 8;
        const float* xr = x + (size_t)row0 * FIN;
        float acc[8];
#pragma unroll
        for (int r = 0; r < 8; ++r) acc[r] = 0.f;
        for (int k = 0; k < FIN; k += 4) {
            float4 xv[8];
#pragma unroll
            for (int r = 0; r < 8; ++r) xv[r] = *(const float4*)(xr + r * FIN + k);
#pragma unroll
            for (int kk = 0; kk < 4; ++kk) {
                float w = W[(size_t)(k + kk) * HID + col];
#pragma unroll
                for (int r = 0; r < 8; ++r)
                    acc[r] = fmaf(((const float*)&xv[r])[kk], w, acc[r]);
            }
        }
#pragma unroll
        for (int r = 0; r < 8; ++r)
            h[(size_t)(row0 + r) * HID + col] = acc[r];
    }

    // ---- grid barrier: all scatter + xw complete ----
    gridbar(bar, GRID_P);

    // ---- phase 2: agg, 8 rows per block (r6 body) ----
    int slot = tid >> 6;  // 0..3 (wave id)
    int fp = tid & 63;    // feature pair index
    const float2* h2 = (const float2*)h;
    __shared__ float part[4][64][2];

    for (int i = 0; i < 8; ++i) {
        int row = bid * 8 + i;
        const int* bin = csr_src + (size_t)row * CAP;

        float ax = 0.f, ay = 0.f;
        unsigned ne = cursor[row];
        for (unsigned e = (unsigned)slot; e < ne; e += 4) {
            int s = bin[e];
            float ds = rsqrtf((float)(cursor[s] + 1u));
            float2 hv = h2[(size_t)s * 64 + fp];
            ax = fmaf(hv.x, ds, ax);
            ay = fmaf(hv.y, ds, ay);
        }
        part[slot][fp][0] = ax;
        part[slot][fp][1] = ay;
        __syncthreads();
        if (slot == 0) {
            float di = rsqrtf((float)(ne + 1u));
            float2 hv = h2[(size_t)row * 64 + fp];
            float sx = (part[0][fp][0] + part[1][fp][0]) + (part[2][fp][0] + part[3][fp][0]) + hv.x * di;
            float sy = (part[0][fp][1] + part[1][fp][1]) + (part[2][fp][1] + part[3][fp][1]) + hv.y * di;
            float2 bb = ((const float2*)b)[fp];
            float zx = fmaxf(fmaf(sx, di, bb.x), 0.f);
            float zy = fmaxf(fmaf(sy, di, bb.y), 0.f);
            ((float2*)z_out)[(size_t)row * 64 + fp] = make_float2(zx, zy);
            unsigned short bx = __builtin_bit_cast(unsigned short, __float2bfloat16(zx));
            unsigned short by = __builtin_bit_cast(unsigned short, __float2bfloat16(zy));
            ((unsigned*)zb)[(size_t)row * 64 + fp] = ((unsigned)by << 16) | (unsigned)bx;
        }
        __syncthreads();  // protect part[] reuse next i
    }
}

// ---- adj = sigmoid(z @ z^T): symmetric, upper-triangle blocks only (r6 form). ----
__global__ __launch_bounds__(256) void gemm_sig(const __hip_bfloat16* __restrict__ zb,
                                                float* __restrict__ adj) {
    int ti = blockIdx.y;
    int tj = blockIdx.x;
    if (tj < ti) return;  // symmetric: skip lower triangle

    int wid = threadIdx.x >> 6;
    int lane = threadIdx.x & 63;
    int wm = wid >> 1, wn = wid & 1;
    int row0 = ti * 128 + wm * 64;
    int col0 = tj * 128 + wn * 64;
    int lr = lane & 15;        // fragment row (A) / row-of-B
    int lk = (lane >> 4) * 8;  // k sub-offset

    f32x4 acc[4][4];
#pragma unroll
    for (int m = 0; m < 4; ++m)
#pragma unroll
        for (int n = 0; n < 4; ++n) acc[m][n] = (f32x4){0.f, 0.f, 0.f, 0.f};

#pragma unroll
    for (int ks = 0; ks < 4; ++ks) {
        int k = ks * 32 + lk;
        bf16x8 a[4], bfr[4];
#pragma unroll
        for (int m = 0; m < 4; ++m)
            a[m] = *(const bf16x8*)(zb + (size_t)(row0 + m * 16 + lr) * HID + k);
#pragma unroll
        for (int n = 0; n < 4; ++n)
            bfr[n] = *(const bf16x8*)(zb + (size_t)(col0 + n * 16 + lr) * HID + k);
#pragma unroll
        for (int m = 0; m < 4; ++m)
#pragma unroll
            for (int n = 0; n < 4; ++n)
                acc[m][n] = __builtin_amdgcn_mfma_f32_16x16x32_bf16(a[m], bfr[n], acc[m][n], 0, 0, 0);
    }

    int orow = (lane >> 4) * 4;
    bool mirror = (ti != tj);
#pragma unroll
    for (int m = 0; m < 4; ++m) {
        int rowb = row0 + m * 16 + orow;  // multiple of 4 -> 16B-aligned stores
#pragma unroll
        for (int n = 0; n < 4; ++n) {
            int col = col0 + n * 16 + lr;
            f32x4 s4;
#pragma unroll
            for (int r = 0; r < 4; ++r) {
                float v = acc[m][n][r];
                s4[r] = __builtin_amdgcn_rcpf(1.0f + __expf(-v));
            }
            // v = z[row]·z[col]; symmetric => adj[col][row] = adj[row][col].
            *(f32x4*)(adj + (size_t)col * N_NODES + rowb) = s4;
            if (mirror) {
#pragma unroll
                for (int r = 0; r < 4; ++r)
                    adj[(size_t)(rowb + r) * N_NODES + col] = s4[r];
            }
        }
    }
}

extern "C" void kernel_launch(void* const* d_in, const int* in_sizes, int n_in,
                              void* d_out, int out_size, void* d_ws, size_t ws_size,
                              hipStream_t stream) {
    const float* x = (const float*)d_in[0];
    const int* ei = (const int*)d_in[1];
    const float* W = (const float*)d_in[2];
    const float* b = (const float*)d_in[3];
    const int* src = ei;
    const int* dst = ei + E_EDGES;

    float* adj = (float*)d_out;
    float* z_out = (float*)d_out + (size_t)N_NODES * N_NODES;

    char* ws = (char*)d_ws;
    float* h = (float*)ws;                                    // 4 MB
    __hip_bfloat16* zb = (__hip_bfloat16*)(ws + (4u << 20));  // 2 MB
    unsigned* cursor = (unsigned*)(ws + (6u << 20));          // 32 KB
    unsigned* bar = (unsigned*)(ws + (6u << 20) + (32u << 10));  // 256 B
    int* csr = (int*)(ws + (6u << 20) + (64u << 10));         // 4 MB (8192*128*4)

    // zero cursor + barrier counters in one memset node
    hipMemsetAsync(cursor, 0, (32u << 10) + 256, stream);
    hipLaunchKernelGGL(prep_fused, dim3(GRID_P), dim3(256), 0, stream,
                       x, W, src, dst, cursor, csr, b, z_out, zb, h, bar);
    hipLaunchKernelGGL(gemm_sig, dim3(64, 64), dim3(256), 0, stream, zb, adj);
}

// Round 11
// 145.730 us; speedup vs baseline: 2.0076x; 2.0076x over previous
//
#include <hip/hip_runtime.h>
#include <hip/hip_bf16.h>

#define N_NODES 8192
#define E_EDGES 262144
#define HID 128
#define FIN 256
#define CAP 128  // fixed CSR bin capacity; deg ~ Binom(262144,1/8192), max ~60

typedef __attribute__((ext_vector_type(8))) short bf16x8;
typedef __attribute__((ext_vector_type(4))) float f32x4;

// ---- h = X @ W (fp32 vector). 16 rows/block. Also zeroes cursor (runs first). ----
__global__ __launch_bounds__(256) void xw_kernel(const float* __restrict__ x,
                                                 const float* __restrict__ W,
                                                 float* __restrict__ h,
                                                 unsigned* __restrict__ cursor) {
    if (blockIdx.x < 32) cursor[blockIdx.x * 256 + threadIdx.x] = 0u;

    int col = threadIdx.x & 127;
    int row0 = blockIdx.x * 16 + (threadIdx.x >> 7) * 8;
    const float* xr = x + (size_t)row0 * FIN;
    float acc[8];
#pragma unroll
    for (int r = 0; r < 8; ++r) acc[r] = 0.f;

    for (int k = 0; k < FIN; k += 4) {
        float4 xv[8];
#pragma unroll
        for (int r = 0; r < 8; ++r) xv[r] = *(const float4*)(xr + r * FIN + k);
#pragma unroll
        for (int kk = 0; kk < 4; ++kk) {
            float w = W[(size_t)(k + kk) * HID + col];
#pragma unroll
            for (int r = 0; r < 8; ++r)
                acc[r] = fmaf(((const float*)&xv[r])[kk], w, acc[r]);
        }
    }
#pragma unroll
    for (int r = 0; r < 8; ++r)
        h[(size_t)(row0 + r) * HID + col] = acc[r];
}

// ---- scatter edges into fixed-capacity CSR bins (by dst); cursor ends as deg count ----
__global__ void scatter_csr(const int* __restrict__ src, const int* __restrict__ dst,
                            unsigned* __restrict__ cursor, int* __restrict__ csr_src) {
    int e = blockIdx.x * 256 + threadIdx.x;
    if (e < E_EDGES) {
        int d = dst[e];
        unsigned pos = atomicAdd(&cursor[d], 1u);
        csr_src[(size_t)d * CAP + pos] = src[e];
    }
}

// ---- sym-normalized aggregation + bias + relu; 4 edge-slots in flight ----
__global__ __launch_bounds__(256) void agg_kernel(const float* __restrict__ h,
                                                  const unsigned* __restrict__ cnt,
                                                  const int* __restrict__ csr_src,
                                                  const float* __restrict__ b,
                                                  float* __restrict__ z_out,
                                                  __hip_bfloat16* __restrict__ zb) {
    int row = blockIdx.x;
    int slot = threadIdx.x >> 6;  // 0..3 (wave id)
    int fp = threadIdx.x & 63;    // feature pair index
    const float2* h2 = (const float2*)h;
    const int* bin = csr_src + (size_t)row * CAP;

    float ax = 0.f, ay = 0.f;
    unsigned ne = cnt[row];
    for (unsigned e = (unsigned)slot; e < ne; e += 4) {
        int s = bin[e];
        float ds = rsqrtf((float)(cnt[s] + 1u));  // same value as old dinv[s]
        float2 hv = h2[(size_t)s * 64 + fp];
        ax = fmaf(hv.x, ds, ax);
        ay = fmaf(hv.y, ds, ay);
    }
    __shared__ float part[4][64][2];
    part[slot][fp][0] = ax;
    part[slot][fp][1] = ay;
    __syncthreads();
    if (slot == 0) {
        float di = rsqrtf((float)(ne + 1u));
        float2 hv = h2[(size_t)row * 64 + fp];
        float sx = (part[0][fp][0] + part[1][fp][0]) + (part[2][fp][0] + part[3][fp][0]) + hv.x * di;
        float sy = (part[0][fp][1] + part[1][fp][1]) + (part[2][fp][1] + part[3][fp][1]) + hv.y * di;
        float2 bb = ((const float2*)b)[fp];
        float zx = fmaxf(fmaf(sx, di, bb.x), 0.f);
        float zy = fmaxf(fmaf(sy, di, bb.y), 0.f);
        ((float2*)z_out)[(size_t)row * 64 + fp] = make_float2(zx, zy);
        unsigned short bx = __builtin_bit_cast(unsigned short, __float2bfloat16(zx));
        unsigned short by = __builtin_bit_cast(unsigned short, __float2bfloat16(zy));
        ((unsigned*)zb)[(size_t)row * 64 + fp] = ((unsigned)by << 16) | (unsigned)bx;
    }
}

// ---- adj = sigmoid(z @ z^T): triangle at 512x512 super-tile granularity.
// 136 super-tiles (TJ>=TI) x 8 row-strips = 1088 blocks; each block = 64 adj
// rows x 512 adj cols (r8 wave layout). Primary: row-major scalar stores ->
// 2KB contiguous run per adj-row (r8 measured long runs worth ~27us). Mirror
// (TI!=TJ): acc's 4 consecutive rows -> float4 stores at adj[col][row], full
// 64B lines, runs chain across the 8 strips. Diagonal super-tiles computed
// full (+6% compute vs perfect triangle). ----
__global__ __launch_bounds__(256) void gemm_sig(const __hip_bfloat16* __restrict__ zb,
                                                float* __restrict__ adj) {
    int strip = blockIdx.x & 7;
    int p = blockIdx.x >> 3;  // 0..135 triangular pair index
    int TI = 0, rem = p;
    while (rem >= 16 - TI) { rem -= 16 - TI; ++TI; }
    int TJ = TI + rem;

    int wid = threadIdx.x >> 6;
    int lane = threadIdx.x & 63;
    int lr = lane & 15;  // fragment index
    int hi = lane >> 4;  // 0..3
    int lk = hi * 8;     // k sub-offset

    int row0 = TI * 512 + strip * 64;      // adj rows (A = z rows)
    int col0 = TJ * 512 + wid * 128;       // adj cols (B = z rows)

    f32x4 acc[4][8];
#pragma unroll
    for (int m = 0; m < 4; ++m)
#pragma unroll
        for (int n = 0; n < 8; ++n) acc[m][n] = (f32x4){0.f, 0.f, 0.f, 0.f};

#pragma unroll
    for (int ks = 0; ks < 4; ++ks) {
        int k = ks * 32 + lk;
        bf16x8 a[4], bfr[8];
#pragma unroll
        for (int m = 0; m < 4; ++m)
            a[m] = *(const bf16x8*)(zb + (size_t)(row0 + m * 16 + lr) * HID + k);
#pragma unroll
        for (int n = 0; n < 8; ++n)
            bfr[n] = *(const bf16x8*)(zb + (size_t)(col0 + n * 16 + lr) * HID + k);
#pragma unroll
        for (int m = 0; m < 4; ++m)
#pragma unroll
            for (int n = 0; n < 8; ++n)
                acc[m][n] = __builtin_amdgcn_mfma_f32_16x16x32_bf16(a[m], bfr[n], acc[m][n], 0, 0, 0);
    }

    int orow = hi * 4;
    bool mirror = (TI != TJ);
#pragma unroll
    for (int m = 0; m < 4; ++m) {
        int rowb = row0 + m * 16 + orow;  // multiple of 4
#pragma unroll
        for (int n = 0; n < 8; ++n) {
            int col = col0 + n * 16 + lr;
            f32x4 s4;
#pragma unroll
            for (int r = 0; r < 4; ++r) {
                float v = acc[m][n][r];
                s4[r] = __builtin_amdgcn_rcpf(1.0f + __expf(-v));
            }
            // primary row-major: per (m,n,r) instr wave covers 4 rows x 16
            // consecutive cols = 4 full 64B lines; 2KB runs per adj-row.
#pragma unroll
            for (int r = 0; r < 4; ++r)
                adj[(size_t)(rowb + r) * N_NODES + col] = s4[r];
            // mirror: adj[col][rowb..rowb+3] = same values (symmetry), float4.
            if (mirror)
                *(f32x4*)(adj + (size_t)col * N_NODES + rowb) = s4;
        }
    }
}

extern "C" void kernel_launch(void* const* d_in, const int* in_sizes, int n_in,
                              void* d_out, int out_size, void* d_ws, size_t ws_size,
                              hipStream_t stream) {
    const float* x = (const float*)d_in[0];
    const int* ei = (const int*)d_in[1];
    const float* W = (const float*)d_in[2];
    const float* b = (const float*)d_in[3];
    const int* src = ei;
    const int* dst = ei + E_EDGES;

    float* adj = (float*)d_out;
    float* z_out = (float*)d_out + (size_t)N_NODES * N_NODES;

    char* ws = (char*)d_ws;
    float* h = (float*)ws;                                    // 4 MB
    __hip_bfloat16* zb = (__hip_bfloat16*)(ws + (4u << 20));  // 2 MB
    unsigned* cursor = (unsigned*)(ws + (6u << 20));          // 32 KB
    int* csr = (int*)(ws + (6u << 20) + (32u << 10));         // 4 MB (8192*128*4)

    // xw first: independent of edges, also zeroes cursor for scatter.
    hipLaunchKernelGGL(xw_kernel, dim3(N_NODES / 16), dim3(256), 0, stream, x, W, h, cursor);
    hipLaunchKernelGGL(scatter_csr, dim3(E_EDGES / 256), dim3(256), 0, stream, src, dst, cursor, csr);
    hipLaunchKernelGGL(agg_kernel, dim3(N_NODES), dim3(256), 0, stream, h, cursor, csr, b, z_out, zb);
    hipLaunchKernelGGL(gemm_sig, dim3(136 * 8), dim3(256), 0, stream, zb, adj);
}